// Round 8
// baseline (621.237 us; speedup 1.0000x reference)
//
#include <hip/hip_runtime.h>

typedef __attribute__((ext_vector_type(4))) float floatx4;
typedef __attribute__((ext_vector_type(8))) short shortx8;
typedef __attribute__((ext_vector_type(4))) short shortx4;
typedef __attribute__((ext_vector_type(4))) int intx4;
typedef __attribute__((ext_vector_type(2))) int intx2;

#define DEVI static __device__ __forceinline__

constexpr int NN = 20000;   // nodes
constexpr int NE = 640000;  // edges
constexpr int PREP_BLOCKS = 404;   // 103184 prep items / 256
constexpr int HIST_BLOCKS = NE / 256;  // 2500
constexpr int AGGZ_BLOCKS = 1875;  // 7.68MB agg zero, 4KB/block
constexpr int SCAT_BLOCKS = NE / 256;  // 2500
constexpr int NODE_BLOCKS = (NN + 63) / 64;  // 313
constexpr int EDGE_BLOCKS = NE / 64;   // 10000 (round-3 structure)

// ---- workspace layout (bytes) ----
constexpr size_t W1ET_OFF = 0;                          // [128][32] bf16
constexpr size_t WLEN_OFF = 8192;                       // [128] f32
constexpr size_t WCAT_OFF = 8704;                       // [256][160] bf16
constexpr size_t W2GT_OFF = 90624;                      // [16][128] bf16 (W2@Wg, gate)
constexpr size_t CG_OFF   = 94720;                      // [16] f32 (b2@Wg + bg)
constexpr size_t U1T_OFF  = 94784;                      // [128][288] bf16 (rows128:256=W2@U1b)
constexpr size_t B2U_OFF  = 168512;                     // [128] f32 (b2@U1b)
constexpr size_t U2T_OFF  = 169024;                     // [128][128] bf16
constexpr size_t UGT_OFF  = 201792;                     // [16][128] bf16
constexpr size_t UWVT_OFF = 205888;                     // [16][32] bf16 (Uwv^T)
constexpr size_t ASRC_OFF = 206912;                     // [N][128] bf16 (col-transposed)
constexpr size_t ADST_OFF = ASRC_OFF + (size_t)NN * 128 * 2;
constexpr size_t BSRC_OFF = ADST_OFF + (size_t)NN * 128 * 2;   // [N][16][4] bf16
constexpr size_t BDST_OFF = BSRC_OFF + (size_t)NN * 64 * 2;
constexpr size_t AGG_S_OFF = BDST_OFF + (size_t)NN * 64 * 2;   // [N][128] bf16 (silu sums)
constexpr size_t AGG_V_OFF = AGG_S_OFF + (size_t)NN * 128 * 2; // [N][16][4] bf16
constexpr size_t CNT_OFF  = AGG_V_OFF + (size_t)NN * 64 * 2;   // [N] int (dst degree)
constexpr size_t OFF_OFF  = CNT_OFF + (size_t)NN * 4;          // [N] int (CSR offsets)
constexpr size_t PERM_OFF = OFF_OFF + (size_t)NN * 4;          // [E] int (sorted->orig)
constexpr size_t SD_OFF   = PERM_OFF + (size_t)NE * 4;         // [E] int2 (src,dst sorted)
constexpr size_t LEV_OFF  = SD_OFF + (size_t)NE * 8;           // [E] float4 (xyz+len sorted)

DEVI float bf2f(short h) {
  union { unsigned u; float f; } c;
  c.u = ((unsigned)(unsigned short)h) << 16;
  return c.f;
}
DEVI short f2bf(float f) {  // round-to-nearest-even
  union { float f; unsigned u; } c; c.f = f;
  unsigned x = c.u;
  return (short)((x + 0x7fffu + ((x >> 16) & 1u)) >> 16);
}
DEVI int pack2bf(float x, float y) {
  return (int)(unsigned short)f2bf(x) | ((int)(unsigned short)f2bf(y) << 16);
}
DEVI void atom_pk(short* addr, int val) {  // bf16x2 packed atomic add (RNE)
  asm volatile("global_atomic_pk_add_bf16 %0, %1, off" : : "v"(addr), "v"(val) : "memory");
}
DEVI float sigm(float x) { return __builtin_amdgcn_rcpf(1.0f + __expf(-x)); }

DEVI floatx4 mfma16(shortx8 a, shortx8 b, floatx4 c) {
  return __builtin_amdgcn_mfma_f32_16x16x32_bf16(a, b, c, 0, 0, 0);
}

// ------- weight transform prep (+ fused dst histogram + fused agg zero) -------
__global__ void gvp_prep(const float* __restrict__ mW1, const float* __restrict__ mW2,
                         const float* __restrict__ mWg, const float* __restrict__ mb2,
                         const float* __restrict__ mbg, const float* __restrict__ uW1,
                         const float* __restrict__ uW2, const float* __restrict__ uWg,
                         const float* __restrict__ uWv, const int* __restrict__ eidx,
                         short* __restrict__ w1et, float* __restrict__ wlen,
                         short* __restrict__ wcat, short* __restrict__ w2gt,
                         float* __restrict__ cg, short* __restrict__ u1t,
                         float* __restrict__ b2u, short* __restrict__ u2t,
                         short* __restrict__ ugt, short* __restrict__ uwvt,
                         int* __restrict__ cnt, short* __restrict__ aggz) {
  if (blockIdx.x >= PREP_BLOCKS + HIST_BLOCKS) {  // fused agg-zero blocks
    int zb = blockIdx.x - PREP_BLOCKS - HIST_BLOCKS;
    intx4 z4 = {0, 0, 0, 0};
    ((intx4*)aggz)[(size_t)zb * 256 + threadIdx.x] = z4;
    return;
  }
  if (blockIdx.x >= PREP_BLOCKS) {  // fused histogram blocks (cnt pre-zeroed)
    int e = (blockIdx.x - PREP_BLOCKS) * 256 + threadIdx.x;
    if (e < NE) atomicAdd(cnt + eidx[NE + e], 1);
    return;
  }
  int i = blockIdx.x * 256 + threadIdx.x;
  if (i < 4096) { int n = i >> 5, k = i & 31; w1et[i] = f2bf(mW1[(256 + k) * 128 + n]); return; }
  i -= 4096;
  if (i < 128) { wlen[i] = mW1[288 * 128 + i] + mW1[321 * 128 + i]; return; }
  i -= 128;
  if (i < 40960) {  // wcat [256][160]
    int n = i / 160, k = i % 160;
    float val = 0.f;
    if (n < 128) {
      if (k < 128) val = mW1[k * 128 + n];
      else if (k < 144) val = mW1[(161 + k) * 128 + n];   // 289 + (k-128)
    } else {
      int n2 = n - 128;
      if (k < 128) val = mW1[(128 + k) * 128 + n2];
      else if (k < 144) val = mW1[(177 + k) * 128 + n2];  // 305 + (k-128)
    }
    wcat[i] = f2bf(val);
    return;
  }
  i -= 40960;
  if (i < 2048) {  // w2gt[g][k] = sum_c W2[k][c]*Wg[c][g]
    int g = i >> 7, k = i & 127;
    float acc = 0.f;
#pragma unroll 4
    for (int c4 = 0; c4 < 32; ++c4) {
      floatx4 wr = *(const floatx4*)(mW2 + k * 128 + c4 * 4);
      acc += wr[0] * mWg[(c4 * 4 + 0) * 16 + g] + wr[1] * mWg[(c4 * 4 + 1) * 16 + g] +
             wr[2] * mWg[(c4 * 4 + 2) * 16 + g] + wr[3] * mWg[(c4 * 4 + 3) * 16 + g];
    }
    w2gt[i] = f2bf(acc);
    return;
  }
  i -= 2048;
  if (i < 16) {  // cg[g] = bg[g] + sum_c b2[c]*Wg[c][g]
    float acc = mbg[i];
    for (int c = 0; c < 128; ++c) acc += mb2[c] * mWg[c * 16 + i];
    cg[i] = acc;
    return;
  }
  i -= 16;
  if (i < 36864) {  // u1t [128 n][288 k]; rows 128:256 get W2@U1b
    int n = i / 288, k = i % 288;
    if (k < 128 || k >= 256) {
      u1t[i] = f2bf(uW1[k * 128 + n]);
    } else {
      int j = k - 128;
      float acc = 0.f;
#pragma unroll 4
      for (int c4 = 0; c4 < 32; ++c4) {
        floatx4 wr = *(const floatx4*)(mW2 + j * 128 + c4 * 4);
        acc += wr[0] * uW1[(128 + c4 * 4 + 0) * 128 + n] +
               wr[1] * uW1[(128 + c4 * 4 + 1) * 128 + n] +
               wr[2] * uW1[(128 + c4 * 4 + 2) * 128 + n] +
               wr[3] * uW1[(128 + c4 * 4 + 3) * 128 + n];
      }
      u1t[i] = f2bf(acc);
    }
    return;
  }
  i -= 36864;
  if (i < 128) {  // b2u[n] = sum_c b2[c]*U1b[c][n]
    float acc = 0.f;
    for (int c = 0; c < 128; ++c) acc += mb2[c] * uW1[(128 + c) * 128 + i];
    b2u[i] = acc;
    return;
  }
  i -= 128;
  if (i < 16384) { int n = i >> 7, k = i & 127; u2t[i] = f2bf(uW2[k * 128 + n]); return; }
  i -= 16384;
  if (i < 2048) { int g = i >> 7, k = i & 127; ugt[i] = f2bf(uWg[k * 16 + g]); return; }
  i -= 2048;
  if (i < 512) { int w = i >> 5, k = i & 31; uwvt[i] = f2bf(uWv[k * 16 + w]); return; }
}

// ---------------- block-partial scan (1 block, parallel 2nd level) ----------------
__global__ void gvp_scan(const int* __restrict__ cnt, int* __restrict__ off) {
  __shared__ int part[256];
  const int t = threadIdx.x;
  const int base = t * 79;  // 256*79 = 20224 >= NN
  int sum = 0;
  for (int j = 0; j < 79; ++j) {
    int i = base + j;
    if (i < NN) sum += cnt[i];
  }
  part[t] = sum;
  __syncthreads();
  // Hillis-Steele inclusive scan over part[256]
  for (int ofs = 1; ofs < 256; ofs <<= 1) {
    int x = (t >= ofs) ? part[t - ofs] : 0;
    __syncthreads();
    part[t] += x;
    __syncthreads();
  }
  int run = (t == 0) ? 0 : part[t - 1];
  for (int j = 0; j < 79; ++j) {
    int i = base + j;
    if (i < NN) { off[i] = run; run += cnt[i]; }
  }
}

// ---------------- per-node precompute (+ fused edge scatter) ----------------
__global__ __launch_bounds__(256) void gvp_nodepre(
    const int* __restrict__ eidx, const float* __restrict__ ev,
    int* __restrict__ off, int* __restrict__ perm, int* __restrict__ sd,
    float* __restrict__ lev, const float* __restrict__ s,
    const float* __restrict__ v, const short* __restrict__ wcat,
    const float* __restrict__ b1, const float* __restrict__ wv,
    short* __restrict__ Asrc, short* __restrict__ Adst,
    short* __restrict__ Bsrc, short* __restrict__ Bdst) {
  __shared__ __align__(16) short lx[64 * 160];
  if (blockIdx.x < SCAT_BLOCKS) {  // fused scatter: perm + sorted src/dst + xyz/len
    int e = blockIdx.x * 256 + threadIdx.x;
    if (e < NE) {
      int sn = eidx[e], d = eidx[NE + e];
      int pos = atomicAdd(off + d, 1);
      perm[pos] = e;
      intx2 p; p[0] = sn; p[1] = d;
      *(intx2*)(sd + (size_t)pos * 2) = p;
      const float* evp = ev + (size_t)e * 3;
      float x = evp[0], y = evp[1], z = evp[2];
      floatx4 q;
      q[0] = x; q[1] = y; q[2] = z;
      q[3] = sqrtf(fmaxf(x * x + y * y + z * z, 1e-8f));
      *(floatx4*)(lev + (size_t)pos * 4) = q;
    }
    return;
  }
  const int tid = threadIdx.x;
  const int wid = tid >> 6;
  const int lane = tid & 63;
  const int quad = lane >> 4;
  const int l16 = lane & 15;
  const int nb0 = (blockIdx.x - SCAT_BLOCKS) * 64;

  intx4 z4 = {0, 0, 0, 0};
#pragma unroll
  for (int i = 0; i < 4; i++) {
    int idx = tid + i * 256;
    int r = idx >> 4, cc = (idx & 15) * 8;
    int node = nb0 + r;
    union { short sh[8]; intx4 v4; } u;
    u.v4 = z4;
    if (node < NN) {
      const float* sp = s + (size_t)node * 128 + cc;
      floatx4 f0 = *(const floatx4*)sp, f1 = *(const floatx4*)(sp + 4);
#pragma unroll
      for (int j = 0; j < 4; j++) { u.sh[j] = f2bf(f0[j]); u.sh[4 + j] = f2bf(f1[j]); }
    }
    *(intx4*)(lx + r * 160 + cc) = u.v4;
  }
  if (tid < 64) {
    int node = nb0 + tid;
    union { short sh[16]; intx4 v4[2]; } u;
#pragma unroll
    for (int j = 0; j < 16; j++) {
      float nv = 0.f;
      if (node < NN) {
        const float* vp = v + (size_t)node * 48 + j * 3;
        nv = sqrtf(fmaxf(vp[0] * vp[0] + vp[1] * vp[1] + vp[2] * vp[2], 1e-8f));
      }
      u.sh[j] = f2bf(nv);
    }
    *(intx4*)(lx + tid * 160 + 128) = u.v4[0];
    *(intx4*)(lx + tid * 160 + 136) = u.v4[1];
    *(intx4*)(lx + tid * 160 + 144) = z4;
    *(intx4*)(lx + tid * 160 + 152) = z4;
  }
  __syncthreads();  // only barrier

  floatx4 acc[16] = {};
#pragma unroll
  for (int kc = 0; kc < 5; kc++) {
    shortx8 a = *(const shortx8*)(lx + (wid * 16 + l16) * 160 + kc * 32 + quad * 8);
#pragma unroll
    for (int nt = 0; nt < 16; nt++) {
      shortx8 b = *(const shortx8*)(wcat + (size_t)(nt * 16 + l16) * 160 + kc * 32 + quad * 8);
      acc[nt] = mfma16(a, b, acc[nt]);
    }
  }

  float b1v[8];
#pragma unroll
  for (int nt = 0; nt < 8; nt++) b1v[nt] = b1[nt * 16 + l16];
#pragma unroll
  for (int i = 0; i < 4; i++) {
    int row = wid * 16 + quad * 4 + i;
    int node = nb0 + row;
    if (node < NN) {
      union { short sh[8]; intx4 v4; } us, ud;
#pragma unroll
      for (int nt = 0; nt < 8; nt++) {
        us.sh[nt] = f2bf(acc[nt][i] + b1v[nt]);
        ud.sh[nt] = f2bf(acc[8 + nt][i]);
      }
      *(intx4*)(Asrc + (size_t)node * 128 + l16 * 8) = us.v4;
      *(intx4*)(Adst + (size_t)node * 128 + l16 * 8) = ud.v4;
    }
  }

  // vector projections (f32 math, bf16 store)
  {
    int node = nb0 + (tid >> 2), sub = tid & 3;
    if (node < NN) {
      float vr[48];
      const float* vp = v + (size_t)node * 48;
#pragma unroll
      for (int j = 0; j < 48; j++) vr[j] = vp[j];
      for (int w = sub * 4; w < sub * 4 + 4; w++) {
        float bs0 = 0, bs1 = 0, bs2 = 0, bd0 = 0, bd1 = 0, bd2 = 0;
#pragma unroll
        for (int j = 0; j < 16; j++) {
          float w0 = wv[j * 16 + w], w1 = wv[(16 + j) * 16 + w];
          bs0 += vr[j * 3 + 0] * w0; bs1 += vr[j * 3 + 1] * w0; bs2 += vr[j * 3 + 2] * w0;
          bd0 += vr[j * 3 + 0] * w1; bd1 += vr[j * 3 + 1] * w1; bd2 += vr[j * 3 + 2] * w1;
        }
        union { short sh[4]; intx2 v2; } ub, ud2;
        ub.sh[0] = f2bf(bs0); ub.sh[1] = f2bf(bs1); ub.sh[2] = f2bf(bs2); ub.sh[3] = 0;
        ud2.sh[0] = f2bf(bd0); ud2.sh[1] = f2bf(bd1); ud2.sh[2] = f2bf(bd2); ud2.sh[3] = 0;
        *(intx2*)(Bsrc + (size_t)node * 64 + w * 4) = ub.v2;
        *(intx2*)(Bdst + (size_t)node * 64 + w * 4) = ud2.v2;
      }
    }
  }
}

// ------- edge message kernel (R3 structure + BLOCK-level agg_s reduction) -------
// 64 sorted edges/block, 4 waves share the window. All silu tiles land in
// block-shared LDS; after a barrier, wave 0 reduces agg_s over BLOCK-level
// dst-runs (~3/block) -> 64 packed atomics per block-run instead of per
// wave-run (~6/block). agg_v stays wave-level (register layout).
__global__ __launch_bounds__(256, 8) void gvp_edge(
    const int* __restrict__ perm, const int* __restrict__ sd,
    const float* __restrict__ lev, const float* __restrict__ es,
    const short* __restrict__ w1et, const float* __restrict__ wlen,
    const short* __restrict__ w2gt, const short* __restrict__ Asrc,
    const short* __restrict__ Adst, const short* __restrict__ Bsrc,
    const short* __restrict__ Bdst, const float* __restrict__ cg,
    const float* __restrict__ wv, short* __restrict__ agg_s,
    short* __restrict__ agg_v) {
  __shared__ __align__(16) short lh_all[4 * 16 * 136];  // per-wave silu tiles
  __shared__ int lpe[64];
  __shared__ int lsrc[64];
  __shared__ int ldst[64];
  __shared__ float lev4[64][4];  // x,y,z,len (pre-sorted table)

  const int tid = threadIdx.x;
  const int wid = tid >> 6;
  const int lane = tid & 63;
  const int quad = lane >> 4;
  const int l16 = lane & 15;
  const int e0 = blockIdx.x * 64;

  if (tid < 64) {
    intx2 p = *(const intx2*)(sd + (size_t)(e0 + tid) * 2);
    lsrc[tid] = p[0];
    ldst[tid] = p[1];
  } else if (tid < 128) {
    int er = tid - 64;
    floatx4 q = *(const floatx4*)(lev + (size_t)(e0 + er) * 4);
    lev4[er][0] = q[0]; lev4[er][1] = q[1]; lev4[er][2] = q[2]; lev4[er][3] = q[3];
  } else if (tid < 192) {
    int er = tid - 128;
    lpe[er] = perm[e0 + er];
  }
  __syncthreads();  // staging barrier

  short* lh = lh_all + wid * 2176;

  // ---- GEMM1e: edge_s @ W1e (K=32), rows via perm (128B rows = full lines) ----
  const int erow = wid * 16 + l16;
  const int pe = lpe[erow];
  const float* ep = es + (size_t)pe * 32 + quad * 8;
  floatx4 ea = *(const floatx4*)ep;
  floatx4 eb = *(const floatx4*)(ep + 4);
  shortx8 afrag;
#pragma unroll
  for (int j = 0; j < 4; j++) { afrag[j] = f2bf(ea[j]); afrag[4 + j] = f2bf(eb[j]); }
  floatx4 acc[8];
#pragma unroll
  for (int nt = 0; nt < 8; nt++) {
    shortx8 b = *(const shortx8*)(w1et + (nt * 16 + l16) * 32 + quad * 8);
    floatx4 z = {0.f, 0.f, 0.f, 0.f};
    acc[nt] = mfma16(afrag, b, z);
  }

  // ---- this lane's 4 edge rows ----
  int srcn[4], dstn[4];
  float lenr[4];
#pragma unroll
  for (int i = 0; i < 4; i++) {
    int r = wid * 16 + quad * 4 + i;
    srcn[i] = lsrc[r]; dstn[i] = ldst[r]; lenr[i] = lev4[r][3];
  }

  // ---- h += A_src[src] + A_dst[dst] (bf16 gathers, f32 add; dst runs L1-hot) ----
#pragma unroll
  for (int i = 0; i < 4; i++) {
    shortx8 s8 = *(const shortx8*)(Asrc + (size_t)srcn[i] * 128 + l16 * 8);
    shortx8 d8 = *(const shortx8*)(Adst + (size_t)dstn[i] * 128 + l16 * 8);
#pragma unroll
    for (int nt = 0; nt < 8; nt++) acc[nt][i] += bf2f(s8[nt]) + bf2f(d8[nt]);
  }
  // ---- h += len * wlen[col] ----
#pragma unroll
  for (int nt = 0; nt < 8; nt++) {
    float wl = wlen[nt * 16 + l16];
#pragma unroll
    for (int i = 0; i < 4; i++) acc[nt][i] += lenr[i] * wl;
  }

  // ---- silu -> per-wave lh (bf16) ----
#pragma unroll
  for (int nt = 0; nt < 8; nt++)
#pragma unroll
    for (int i = 0; i < 4; i++) {
      float h = acc[nt][i];
      lh[(quad * 4 + i) * 136 + nt * 16 + l16] = f2bf(h * sigm(h));
    }
  __syncthreads();  // all 4 silu tiles visible block-wide

  // ---- gate logits = silu(h) @ W2g (K=128) ----
  floatx4 acc3 = {0.f, 0.f, 0.f, 0.f};
#pragma unroll
  for (int kc = 0; kc < 4; kc++) {
    shortx8 a = *(const shortx8*)(lh + l16 * 136 + kc * 32 + quad * 8);
    shortx8 b = *(const shortx8*)(w2gt + l16 * 128 + kc * 32 + quad * 8);
    acc3 = mfma16(a, b, acc3);
  }

  // ---- gated vproj into registers ----
  float wv32v = wv[32 * 16 + l16];
  float cgv = cg[l16];
  float gv[4][3];
#pragma unroll
  for (int i = 0; i < 4; i++) {
    int r = wid * 16 + quad * 4 + i;
    shortx4 bs = *(const shortx4*)(Bsrc + (size_t)srcn[i] * 64 + l16 * 4);
    shortx4 bd = *(const shortx4*)(Bdst + (size_t)dstn[i] * 64 + l16 * 4);
    float vx = bf2f(bs[0]) + bf2f(bd[0]) + lev4[r][0] * wv32v;
    float vy = bf2f(bs[1]) + bf2f(bd[1]) + lev4[r][1] * wv32v;
    float vz = bf2f(bs[2]) + bf2f(bd[2]) + lev4[r][2] * wv32v;
    float g = sigm(acc3[i] + cgv);
    gv[i][0] = g * vx; gv[i][1] = g * vy; gv[i][2] = g * vz;
  }

  // ---- agg_v: wave-level run flush (register layout; unchanged from R3) ----
  const int rbase = wid * 16;
  int r = 0;
  while (r < 16) {
    int d = ldst[rbase + r];
    int r2 = r + 1;
    while (r2 < 16 && ldst[rbase + r2] == d) ++r2;
    float vx = 0.f, vy = 0.f, vz = 0.f;
#pragma unroll
    for (int i = 0; i < 4; ++i) {
      int row = quad * 4 + i;
      if (row >= r && row < r2) { vx += gv[i][0]; vy += gv[i][1]; vz += gv[i][2]; }
    }
    vx += __shfl_xor(vx, 16); vy += __shfl_xor(vy, 16); vz += __shfl_xor(vz, 16);
    vx += __shfl_xor(vx, 32); vy += __shfl_xor(vy, 32); vz += __shfl_xor(vz, 32);
    if (quad == 0) {
      short* ap = agg_v + (size_t)d * 64 + l16 * 4;
      atom_pk(ap, pack2bf(vx, vy));
      atom_pk(ap + 2, pack2bf(vz, 0.f));
    }
    r = r2;
  }

  // ---- agg_s: BLOCK-level run reduction by wave 0 (lane t owns cols 2t,2t+1) ----
  if (tid < 64) {
    int rr = 0;
    while (rr < 64) {
      int d = ldst[rr];
      int r2 = rr + 1;
      while (r2 < 64 && ldst[r2] == d) ++r2;
      float s0 = 0.f, s1 = 0.f;
      for (int row = rr; row < r2; ++row) {
        int pv = *(const int*)(lh_all + (row >> 4) * 2176 + (row & 15) * 136 + 2 * tid);
        s0 += bf2f((short)(pv & 0xffff));
        s1 += bf2f((short)((unsigned)pv >> 16));
      }
      atom_pk(agg_s + (size_t)d * 128 + 2 * tid, pack2bf(s0, s1));
      rr = r2;
    }
  }
}

// ---------------- node update kernel (2 barriers) ----------------
__global__ __launch_bounds__(256) void gvp_node(
    const float* __restrict__ s, const float* __restrict__ v,
    const short* __restrict__ agg_s, const short* __restrict__ agg_v,
    const int* __restrict__ cnt, const float* __restrict__ b2u,
    const short* __restrict__ u1t, const short* __restrict__ u2t,
    const short* __restrict__ ugt, const short* __restrict__ uwvt,
    const float* __restrict__ b1, const float* __restrict__ b2,
    const float* __restrict__ bg, const float* __restrict__ lng,
    const float* __restrict__ lnb, float* __restrict__ out_s,
    float* __restrict__ out_v) {
  __shared__ __align__(16) short lx[64 * 288];  // X2 [64][288]; overlays: lh + lb
  const int tid = threadIdx.x;
  const int wid = tid >> 6;
  const int lane = tid & 63;
  const int quad = lane >> 4;
  const int l16 = lane & 15;
  const int nb0 = blockIdx.x * 64;

  float cntf[4];
#pragma unroll
  for (int i = 0; i < 4; i++) {
    int node = nb0 + wid * 16 + quad * 4 + i;
    cntf[i] = (node < NN) ? (float)cnt[node] : 0.f;
  }

  intx4 z4 = {0, 0, 0, 0};
#pragma unroll
  for (int i = 0; i < 4; i++) {
    int idx = tid + i * 256;
    int r = idx >> 4, cc = (idx & 15) * 8;
    int node = nb0 + r;
    union { short sh[8]; intx4 v4; } u;
    u.v4 = z4;
    if (node < NN) {
      const float* sp = s + (size_t)node * 128 + cc;
      floatx4 f0 = *(const floatx4*)sp, f1 = *(const floatx4*)(sp + 4);
#pragma unroll
      for (int j = 0; j < 4; j++) { u.sh[j] = f2bf(f0[j]); u.sh[4 + j] = f2bf(f1[j]); }
    }
    *(intx4*)(lx + r * 288 + cc) = u.v4;
  }
#pragma unroll
  for (int i = 0; i < 4; i++) {  // agg_silu: already bf16, straight copy
    int idx = tid + i * 256;
    int r = idx >> 4, cc = (idx & 15) * 8;
    int node = nb0 + r;
    intx4 val = z4;
    if (node < NN) val = *(const intx4*)(agg_s + (size_t)node * 128 + cc);
    *(intx4*)(lx + r * 288 + 128 + cc) = val;
  }
  {
    int r = tid >> 2, p = tid & 3;
    int node = nb0 + r;
    int w0 = (p & 1) * 8;
    if (p < 2) {
#pragma unroll
      for (int w = 0; w < 8; w++) {
        float nv = 0.f;
        if (node < NN) {
          const float* vp = v + (size_t)node * 48 + (w0 + w) * 3;
          nv = sqrtf(fmaxf(vp[0] * vp[0] + vp[1] * vp[1] + vp[2] * vp[2], 1e-8f));
        }
        lx[r * 288 + 256 + w0 + w] = f2bf(nv);
      }
    } else {
#pragma unroll
      for (int w = 0; w < 8; w++) {
        float nv = 0.f;
        if (node < NN) {
          const short* ap = agg_v + (size_t)node * 64 + (w0 + w) * 4;
          float x = bf2f(ap[0]), y = bf2f(ap[1]), zz = bf2f(ap[2]);
          nv = sqrtf(fmaxf(x * x + y * y + zz * zz, 1e-8f));
        }
        lx[r * 288 + 272 + w0 + w] = f2bf(nv);
      }
    }
  }
  __syncthreads();  // X2 ready

  // ---- GEMM1 (K=288), B-frags from global u1t ----
  floatx4 acc[8] = {};
#pragma unroll
  for (int kc = 0; kc < 9; kc++) {
    shortx8 a = *(const shortx8*)(lx + (wid * 16 + l16) * 288 + kc * 32 + quad * 8);
#pragma unroll
    for (int nt = 0; nt < 8; nt++) {
      shortx8 b = *(const shortx8*)(u1t + (size_t)(nt * 16 + l16) * 288 + kc * 32 + quad * 8);
      acc[nt] = mfma16(a, b, acc[nt]);
    }
  }
  __syncthreads();  // X2 dead; safe to overlay lh/lb

  short* lh = lx;  // [64][136] bf16
  short* lb = lx + 8704 + wid * 1536;  // per-wave [3 comp][16 node][32 k] bf16
#pragma unroll
  for (int nt = 0; nt < 8; nt++)
#pragma unroll
    for (int i = 0; i < 4; i++) {
      int row = wid * 16 + quad * 4 + i;
      int col = nt * 16 + l16;
      float h = acc[nt][i] + b1[col] + cntf[i] * b2u[col];
      lh[row * 136 + col] = f2bf(h * sigm(h));
    }

  // ---- GEMM2 (K=128), B from global u2t ----
  floatx4 acc2[8] = {};
#pragma unroll
  for (int kc = 0; kc < 4; kc++) {
    shortx8 a = *(const shortx8*)(lh + (wid * 16 + l16) * 136 + kc * 32 + quad * 8);
#pragma unroll
    for (int nt = 0; nt < 8; nt++) {
      shortx8 b = *(const shortx8*)(u2t + (size_t)(nt * 16 + l16) * 128 + kc * 32 + quad * 8);
      acc2[nt] = mfma16(a, b, acc2[nt]);
    }
  }

  // ---- epilogue: ds -> lh (gate input); t = s + ds in acc2 ----
#pragma unroll
  for (int nt = 0; nt < 8; nt++)
#pragma unroll
    for (int i = 0; i < 4; i++) {
      int row = wid * 16 + quad * 4 + i;
      int col = nt * 16 + l16;
      int node = nb0 + row;
      float ds = acc2[nt][i] + b2[col];
      lh[row * 136 + col] = f2bf(ds);
      float sv = (node < NN) ? s[(size_t)node * 128 + col] : 0.f;
      acc2[nt][i] = sv + ds;
    }

  // ---- LayerNorm + out_s store ----
#pragma unroll
  for (int i = 0; i < 4; i++) {
    float sum = 0.f, sq = 0.f;
#pragma unroll
    for (int nt = 0; nt < 8; nt++) { float t = acc2[nt][i]; sum += t; sq += t * t; }
    for (int off2 = 1; off2 < 16; off2 <<= 1) {
      sum += __shfl_xor(sum, off2);
      sq += __shfl_xor(sq, off2);
    }
    float mean = sum * (1.f / 128.f);
    float var = sq * (1.f / 128.f) - mean * mean;
    float inv = rsqrtf(fmaxf(var, 0.f) + 1e-5f);
    int node = nb0 + wid * 16 + quad * 4 + i;
    if (node < NN) {
#pragma unroll
      for (int nt = 0; nt < 8; nt++) {
        int col = nt * 16 + l16;
        float o = (acc2[nt][i] - mean) * inv * lng[col] + lnb[col];
        out_s[(size_t)node * 128 + col] = o;
      }
    }
  }

  // ---- per-wave u_v_in tile lb [3][16 node][32 ch] bf16 (wave-local) ----
  {
    int e = lane >> 2, p = lane & 3;
    int node = nb0 + wid * 16 + e;
    short* lbe = lb + e * 32;
    if (p < 2) {  // v channels k = p*8 .. p*8+7
      float vr[24];
      if (node < NN) {
        const floatx4* sp = (const floatx4*)(v + (size_t)node * 48 + p * 24);
#pragma unroll
        for (int j = 0; j < 6; j++) {
          floatx4 f = sp[j];
          vr[j * 4 + 0] = f[0]; vr[j * 4 + 1] = f[1];
          vr[j * 4 + 2] = f[2]; vr[j * 4 + 3] = f[3];
        }
      } else {
#pragma unroll
        for (int j = 0; j < 24; j++) vr[j] = 0.f;
      }
#pragma unroll
      for (int k = 0; k < 8; k++)
#pragma unroll
        for (int c = 0; c < 3; c++)
          lbe[c * 512 + p * 8 + k] = f2bf(vr[k * 3 + c]);
    } else {  // agg_v channels k = 16 + (p-2)*8 ..
      int wbase = (p - 2) * 8;
#pragma unroll
      for (int w = 0; w < 8; w++) {
        shortx4 av = {0, 0, 0, 0};
        if (node < NN) av = *(const shortx4*)(agg_v + (size_t)node * 64 + (wbase + w) * 4);
#pragma unroll
        for (int c = 0; c < 3; c++)
          lbe[c * 512 + 16 + wbase + w] = av[c];
      }
    }
  }

  // ---- GEMM3: gate logits = ds @ Ug (B from global) ----
  floatx4 acc3 = {0.f, 0.f, 0.f, 0.f};
#pragma unroll
  for (int kc = 0; kc < 4; kc++) {
    shortx8 a = *(const shortx8*)(lh + (wid * 16 + l16) * 136 + kc * 32 + quad * 8);
    shortx8 b = *(const shortx8*)(ugt + l16 * 128 + kc * 32 + quad * 8);
    acc3 = mfma16(a, b, acc3);
  }

  // ---- dv via 3 MFMAs ----
  float vm[4][3];
#pragma unroll
  for (int c = 0; c < 3; c++) {
    shortx8 a = *(const shortx8*)(lb + c * 512 + l16 * 32 + quad * 8);
    shortx8 b = *(const shortx8*)(uwvt + l16 * 32 + quad * 8);
    floatx4 z = {0.f, 0.f, 0.f, 0.f};
    floatx4 rr = mfma16(a, b, z);
#pragma unroll
    for (int i = 0; i < 4; i++) vm[i][c] = rr[i];
  }

  // ---- residual store ----
#pragma unroll
  for (int i = 0; i < 4; i++) {
    int node = nb0 + wid * 16 + quad * 4 + i;
    if (node < NN) {
      float g = sigm(acc3[i] + bg[l16]);
      size_t base = (size_t)node * 48 + l16 * 3;
      out_v[base + 0] = v[base + 0] + g * vm[i][0];
      out_v[base + 1] = v[base + 1] + g * vm[i][1];
      out_v[base + 2] = v[base + 2] + g * vm[i][2];
    }
  }
}

extern "C" void kernel_launch(void* const* d_in, const int* in_sizes, int n_in,
                              void* d_out, int out_size, void* d_ws, size_t ws_size,
                              hipStream_t stream) {
  const float* s = (const float*)d_in[0];
  const float* v = (const float*)d_in[1];
  const int* eidx = (const int*)d_in[2];
  const float* es = (const float*)d_in[3];
  const float* ev = (const float*)d_in[4];
  const float* mW1 = (const float*)d_in[5];
  const float* mb1 = (const float*)d_in[6];
  const float* mW2 = (const float*)d_in[7];
  const float* mb2 = (const float*)d_in[8];
  const float* mWv = (const float*)d_in[9];
  const float* mWg = (const float*)d_in[10];
  const float* mbg = (const float*)d_in[11];
  const float* uW1 = (const float*)d_in[12];
  const float* ub1 = (const float*)d_in[13];
  const float* uW2 = (const float*)d_in[14];
  const float* ub2 = (const float*)d_in[15];
  const float* uWv = (const float*)d_in[16];
  const float* uWg = (const float*)d_in[17];
  const float* ubg = (const float*)d_in[18];
  const float* lng = (const float*)d_in[19];
  const float* lnb = (const float*)d_in[20];

  char* ws = (char*)d_ws;
  short* w1et = (short*)(ws + W1ET_OFF);
  float* wlen = (float*)(ws + WLEN_OFF);
  short* wcat = (short*)(ws + WCAT_OFF);
  short* w2gt = (short*)(ws + W2GT_OFF);
  float* cg = (float*)(ws + CG_OFF);
  short* u1t = (short*)(ws + U1T_OFF);
  float* b2u = (float*)(ws + B2U_OFF);
  short* u2t = (short*)(ws + U2T_OFF);
  short* ugt = (short*)(ws + UGT_OFF);
  short* uwvt = (short*)(ws + UWVT_OFF);
  short* Asrc = (short*)(ws + ASRC_OFF);
  short* Adst = (short*)(ws + ADST_OFF);
  short* Bsrc = (short*)(ws + BSRC_OFF);
  short* Bdst = (short*)(ws + BDST_OFF);
  short* agg_s = (short*)(ws + AGG_S_OFF);
  short* agg_v = (short*)(ws + AGG_V_OFF);
  int* cnt = (int*)(ws + CNT_OFF);
  int* off = (int*)(ws + OFF_OFF);
  int* perm = (int*)(ws + PERM_OFF);
  int* sd = (int*)(ws + SD_OFF);
  float* lev = (float*)(ws + LEV_OFF);

  hipMemsetAsync(ws + CNT_OFF, 0, (size_t)NN * 4, stream);  // cnt only (80KB)
  gvp_prep<<<PREP_BLOCKS + HIST_BLOCKS + AGGZ_BLOCKS, 256, 0, stream>>>(
      mW1, mW2, mWg, mb2, mbg, uW1, uW2, uWg, uWv, eidx,
      w1et, wlen, wcat, w2gt, cg, u1t, b2u, u2t, ugt, uwvt, cnt, agg_s);
  gvp_scan<<<1, 256, 0, stream>>>(cnt, off);
  gvp_nodepre<<<SCAT_BLOCKS + NODE_BLOCKS, 256, 0, stream>>>(
      eidx, ev, off, perm, sd, lev, s, v, wcat, mb1, mWv, Asrc, Adst, Bsrc, Bdst);
  gvp_edge<<<EDGE_BLOCKS, 256, 0, stream>>>(perm, sd, lev, es, w1et, wlen, w2gt,
                                            Asrc, Adst, Bsrc, Bdst, cg, mWv,
                                            agg_s, agg_v);
  gvp_node<<<NODE_BLOCKS, 256, 0, stream>>>(s, v, agg_s, agg_v, cnt, b2u,
                                            u1t, u2t, ugt, uwvt, ub1, ub2, ubg,
                                            lng, lnb, (float*)d_out,
                                            (float*)d_out + (size_t)NN * 128);
}

// Round 9
// 554.023 us; speedup vs baseline: 1.1213x; 1.1213x over previous
//
#include <hip/hip_runtime.h>

typedef __attribute__((ext_vector_type(4))) float floatx4;
typedef __attribute__((ext_vector_type(8))) short shortx8;
typedef __attribute__((ext_vector_type(4))) short shortx4;
typedef __attribute__((ext_vector_type(4))) int intx4;
typedef __attribute__((ext_vector_type(2))) int intx2;

#define DEVI static __device__ __forceinline__

constexpr int NN = 20000;   // nodes
constexpr int NE = 640000;  // edges
constexpr int PREP_BLOCKS = 404;   // 103184 prep items / 256
constexpr int HIST_BLOCKS = NE / 256;  // 2500
constexpr int AGGZ_BLOCKS = 1875;  // 7.68MB agg zero, 4KB/block
constexpr int SCAT_BLOCKS = NE / 256;  // 2500
constexpr int NODE_BLOCKS = (NN + 63) / 64;  // 313
constexpr int EDGE_BLOCKS = NE / 64;   // 10000 (R3 structure)
constexpr int XCD_CHUNK = EDGE_BLOCKS / 8;  // 1250 windows per XCD

// ---- workspace layout (bytes) ----
constexpr size_t W1ET_OFF = 0;                          // [128][32] bf16
constexpr size_t WLEN_OFF = 8192;                       // [128] f32
constexpr size_t WCAT_OFF = 8704;                       // [256][160] bf16
constexpr size_t W2GT_OFF = 90624;                      // [16][128] bf16 (W2@Wg, gate)
constexpr size_t CG_OFF   = 94720;                      // [16] f32 (b2@Wg + bg)
constexpr size_t U1T_OFF  = 94784;                      // [128][288] bf16 (rows128:256=W2@U1b)
constexpr size_t B2U_OFF  = 168512;                     // [128] f32 (b2@U1b)
constexpr size_t U2T_OFF  = 169024;                     // [128][128] bf16
constexpr size_t UGT_OFF  = 201792;                     // [16][128] bf16
constexpr size_t UWVT_OFF = 205888;                     // [16][32] bf16 (Uwv^T)
constexpr size_t ASRC_OFF = 206912;                     // [N][128] bf16 (col-transposed)
constexpr size_t ADST_OFF = ASRC_OFF + (size_t)NN * 128 * 2;
constexpr size_t BSRC_OFF = ADST_OFF + (size_t)NN * 128 * 2;   // [N][16][4] bf16
constexpr size_t BDST_OFF = BSRC_OFF + (size_t)NN * 64 * 2;
constexpr size_t AGG_S_OFF = BDST_OFF + (size_t)NN * 64 * 2;   // [N][128] bf16 (silu sums)
constexpr size_t AGG_V_OFF = AGG_S_OFF + (size_t)NN * 128 * 2; // [N][16][4] bf16
constexpr size_t CNT_OFF  = AGG_V_OFF + (size_t)NN * 64 * 2;   // [N] int (dst degree)
constexpr size_t OFF_OFF  = CNT_OFF + (size_t)NN * 4;          // [N] int (CSR offsets)
constexpr size_t PERM_OFF = OFF_OFF + (size_t)NN * 4;          // [E] int (sorted->orig)
constexpr size_t SD_OFF   = PERM_OFF + (size_t)NE * 4;         // [E] int2 (src,dst sorted)
constexpr size_t LEV_OFF  = SD_OFF + (size_t)NE * 8;           // [E] float4 (xyz+len sorted)

DEVI float bf2f(short h) {
  union { unsigned u; float f; } c;
  c.u = ((unsigned)(unsigned short)h) << 16;
  return c.f;
}
DEVI short f2bf(float f) {  // round-to-nearest-even
  union { float f; unsigned u; } c; c.f = f;
  unsigned x = c.u;
  return (short)((x + 0x7fffu + ((x >> 16) & 1u)) >> 16);
}
DEVI int pack2bf(float x, float y) {
  return (int)(unsigned short)f2bf(x) | ((int)(unsigned short)f2bf(y) << 16);
}
DEVI void atom_pk(short* addr, int val) {  // bf16x2 packed atomic add (RNE)
  asm volatile("global_atomic_pk_add_bf16 %0, %1, off" : : "v"(addr), "v"(val) : "memory");
}
DEVI float sigm(float x) { return __builtin_amdgcn_rcpf(1.0f + __expf(-x)); }

DEVI floatx4 mfma16(shortx8 a, shortx8 b, floatx4 c) {
  return __builtin_amdgcn_mfma_f32_16x16x32_bf16(a, b, c, 0, 0, 0);
}

// ------- weight transform prep (+ fused dst histogram + fused agg zero) -------
__global__ void gvp_prep(const float* __restrict__ mW1, const float* __restrict__ mW2,
                         const float* __restrict__ mWg, const float* __restrict__ mb2,
                         const float* __restrict__ mbg, const float* __restrict__ uW1,
                         const float* __restrict__ uW2, const float* __restrict__ uWg,
                         const float* __restrict__ uWv, const int* __restrict__ eidx,
                         short* __restrict__ w1et, float* __restrict__ wlen,
                         short* __restrict__ wcat, short* __restrict__ w2gt,
                         float* __restrict__ cg, short* __restrict__ u1t,
                         float* __restrict__ b2u, short* __restrict__ u2t,
                         short* __restrict__ ugt, short* __restrict__ uwvt,
                         int* __restrict__ cnt, short* __restrict__ aggz) {
  if (blockIdx.x >= PREP_BLOCKS + HIST_BLOCKS) {  // fused agg-zero blocks
    int zb = blockIdx.x - PREP_BLOCKS - HIST_BLOCKS;
    intx4 z4 = {0, 0, 0, 0};
    ((intx4*)aggz)[(size_t)zb * 256 + threadIdx.x] = z4;
    return;
  }
  if (blockIdx.x >= PREP_BLOCKS) {  // fused histogram blocks (cnt pre-zeroed)
    int e = (blockIdx.x - PREP_BLOCKS) * 256 + threadIdx.x;
    if (e < NE) atomicAdd(cnt + eidx[NE + e], 1);
    return;
  }
  int i = blockIdx.x * 256 + threadIdx.x;
  if (i < 4096) { int n = i >> 5, k = i & 31; w1et[i] = f2bf(mW1[(256 + k) * 128 + n]); return; }
  i -= 4096;
  if (i < 128) { wlen[i] = mW1[288 * 128 + i] + mW1[321 * 128 + i]; return; }
  i -= 128;
  if (i < 40960) {  // wcat [256][160]
    int n = i / 160, k = i % 160;
    float val = 0.f;
    if (n < 128) {
      if (k < 128) val = mW1[k * 128 + n];
      else if (k < 144) val = mW1[(161 + k) * 128 + n];   // 289 + (k-128)
    } else {
      int n2 = n - 128;
      if (k < 128) val = mW1[(128 + k) * 128 + n2];
      else if (k < 144) val = mW1[(177 + k) * 128 + n2];  // 305 + (k-128)
    }
    wcat[i] = f2bf(val);
    return;
  }
  i -= 40960;
  if (i < 2048) {  // w2gt[g][k] = sum_c W2[k][c]*Wg[c][g]
    int g = i >> 7, k = i & 127;
    float acc = 0.f;
#pragma unroll 4
    for (int c4 = 0; c4 < 32; ++c4) {
      floatx4 wr = *(const floatx4*)(mW2 + k * 128 + c4 * 4);
      acc += wr[0] * mWg[(c4 * 4 + 0) * 16 + g] + wr[1] * mWg[(c4 * 4 + 1) * 16 + g] +
             wr[2] * mWg[(c4 * 4 + 2) * 16 + g] + wr[3] * mWg[(c4 * 4 + 3) * 16 + g];
    }
    w2gt[i] = f2bf(acc);
    return;
  }
  i -= 2048;
  if (i < 16) {  // cg[g] = bg[g] + sum_c b2[c]*Wg[c][g]
    float acc = mbg[i];
    for (int c = 0; c < 128; ++c) acc += mb2[c] * mWg[c * 16 + i];
    cg[i] = acc;
    return;
  }
  i -= 16;
  if (i < 36864) {  // u1t [128 n][288 k]; rows 128:256 get W2@U1b
    int n = i / 288, k = i % 288;
    if (k < 128 || k >= 256) {
      u1t[i] = f2bf(uW1[k * 128 + n]);
    } else {
      int j = k - 128;
      float acc = 0.f;
#pragma unroll 4
      for (int c4 = 0; c4 < 32; ++c4) {
        floatx4 wr = *(const floatx4*)(mW2 + j * 128 + c4 * 4);
        acc += wr[0] * uW1[(128 + c4 * 4 + 0) * 128 + n] +
               wr[1] * uW1[(128 + c4 * 4 + 1) * 128 + n] +
               wr[2] * uW1[(128 + c4 * 4 + 2) * 128 + n] +
               wr[3] * uW1[(128 + c4 * 4 + 3) * 128 + n];
      }
      u1t[i] = f2bf(acc);
    }
    return;
  }
  i -= 36864;
  if (i < 128) {  // b2u[n] = sum_c b2[c]*U1b[c][n]
    float acc = 0.f;
    for (int c = 0; c < 128; ++c) acc += mb2[c] * uW1[(128 + c) * 128 + i];
    b2u[i] = acc;
    return;
  }
  i -= 128;
  if (i < 16384) { int n = i >> 7, k = i & 127; u2t[i] = f2bf(uW2[k * 128 + n]); return; }
  i -= 16384;
  if (i < 2048) { int g = i >> 7, k = i & 127; ugt[i] = f2bf(uWg[k * 16 + g]); return; }
  i -= 2048;
  if (i < 512) { int w = i >> 5, k = i & 31; uwvt[i] = f2bf(uWv[k * 16 + w]); return; }
}

// ---------------- block-partial scan (1 block, parallel 2nd level) ----------------
__global__ void gvp_scan(const int* __restrict__ cnt, int* __restrict__ off) {
  __shared__ int part[256];
  const int t = threadIdx.x;
  const int base = t * 79;  // 256*79 = 20224 >= NN
  int sum = 0;
  for (int j = 0; j < 79; ++j) {
    int i = base + j;
    if (i < NN) sum += cnt[i];
  }
  part[t] = sum;
  __syncthreads();
  // Hillis-Steele inclusive scan over part[256]
  for (int ofs = 1; ofs < 256; ofs <<= 1) {
    int x = (t >= ofs) ? part[t - ofs] : 0;
    __syncthreads();
    part[t] += x;
    __syncthreads();
  }
  int run = (t == 0) ? 0 : part[t - 1];
  for (int j = 0; j < 79; ++j) {
    int i = base + j;
    if (i < NN) { off[i] = run; run += cnt[i]; }
  }
}

// ---------------- per-node precompute (+ fused edge scatter) ----------------
__global__ __launch_bounds__(256) void gvp_nodepre(
    const int* __restrict__ eidx, const float* __restrict__ ev,
    int* __restrict__ off, int* __restrict__ perm, int* __restrict__ sd,
    float* __restrict__ lev, const float* __restrict__ s,
    const float* __restrict__ v, const short* __restrict__ wcat,
    const float* __restrict__ b1, const float* __restrict__ wv,
    short* __restrict__ Asrc, short* __restrict__ Adst,
    short* __restrict__ Bsrc, short* __restrict__ Bdst) {
  __shared__ __align__(16) short lx[64 * 160];
  if (blockIdx.x < SCAT_BLOCKS) {  // fused scatter: perm + sorted src/dst + xyz/len
    int e = blockIdx.x * 256 + threadIdx.x;
    if (e < NE) {
      int sn = eidx[e], d = eidx[NE + e];
      int pos = atomicAdd(off + d, 1);
      perm[pos] = e;
      intx2 p; p[0] = sn; p[1] = d;
      *(intx2*)(sd + (size_t)pos * 2) = p;
      const float* evp = ev + (size_t)e * 3;
      float x = evp[0], y = evp[1], z = evp[2];
      floatx4 q;
      q[0] = x; q[1] = y; q[2] = z;
      q[3] = sqrtf(fmaxf(x * x + y * y + z * z, 1e-8f));
      *(floatx4*)(lev + (size_t)pos * 4) = q;
    }
    return;
  }
  const int tid = threadIdx.x;
  const int wid = tid >> 6;
  const int lane = tid & 63;
  const int quad = lane >> 4;
  const int l16 = lane & 15;
  const int nb0 = (blockIdx.x - SCAT_BLOCKS) * 64;

  intx4 z4 = {0, 0, 0, 0};
#pragma unroll
  for (int i = 0; i < 4; i++) {
    int idx = tid + i * 256;
    int r = idx >> 4, cc = (idx & 15) * 8;
    int node = nb0 + r;
    union { short sh[8]; intx4 v4; } u;
    u.v4 = z4;
    if (node < NN) {
      const float* sp = s + (size_t)node * 128 + cc;
      floatx4 f0 = *(const floatx4*)sp, f1 = *(const floatx4*)(sp + 4);
#pragma unroll
      for (int j = 0; j < 4; j++) { u.sh[j] = f2bf(f0[j]); u.sh[4 + j] = f2bf(f1[j]); }
    }
    *(intx4*)(lx + r * 160 + cc) = u.v4;
  }
  if (tid < 64) {
    int node = nb0 + tid;
    union { short sh[16]; intx4 v4[2]; } u;
#pragma unroll
    for (int j = 0; j < 16; j++) {
      float nv = 0.f;
      if (node < NN) {
        const float* vp = v + (size_t)node * 48 + j * 3;
        nv = sqrtf(fmaxf(vp[0] * vp[0] + vp[1] * vp[1] + vp[2] * vp[2], 1e-8f));
      }
      u.sh[j] = f2bf(nv);
    }
    *(intx4*)(lx + tid * 160 + 128) = u.v4[0];
    *(intx4*)(lx + tid * 160 + 136) = u.v4[1];
    *(intx4*)(lx + tid * 160 + 144) = z4;
    *(intx4*)(lx + tid * 160 + 152) = z4;
  }
  __syncthreads();  // only barrier

  floatx4 acc[16] = {};
#pragma unroll
  for (int kc = 0; kc < 5; kc++) {
    shortx8 a = *(const shortx8*)(lx + (wid * 16 + l16) * 160 + kc * 32 + quad * 8);
#pragma unroll
    for (int nt = 0; nt < 16; nt++) {
      shortx8 b = *(const shortx8*)(wcat + (size_t)(nt * 16 + l16) * 160 + kc * 32 + quad * 8);
      acc[nt] = mfma16(a, b, acc[nt]);
    }
  }

  float b1v[8];
#pragma unroll
  for (int nt = 0; nt < 8; nt++) b1v[nt] = b1[nt * 16 + l16];
#pragma unroll
  for (int i = 0; i < 4; i++) {
    int row = wid * 16 + quad * 4 + i;
    int node = nb0 + row;
    if (node < NN) {
      union { short sh[8]; intx4 v4; } us, ud;
#pragma unroll
      for (int nt = 0; nt < 8; nt++) {
        us.sh[nt] = f2bf(acc[nt][i] + b1v[nt]);
        ud.sh[nt] = f2bf(acc[8 + nt][i]);
      }
      *(intx4*)(Asrc + (size_t)node * 128 + l16 * 8) = us.v4;
      *(intx4*)(Adst + (size_t)node * 128 + l16 * 8) = ud.v4;
    }
  }

  // vector projections (f32 math, bf16 store)
  {
    int node = nb0 + (tid >> 2), sub = tid & 3;
    if (node < NN) {
      float vr[48];
      const float* vp = v + (size_t)node * 48;
#pragma unroll
      for (int j = 0; j < 48; j++) vr[j] = vp[j];
      for (int w = sub * 4; w < sub * 4 + 4; w++) {
        float bs0 = 0, bs1 = 0, bs2 = 0, bd0 = 0, bd1 = 0, bd2 = 0;
#pragma unroll
        for (int j = 0; j < 16; j++) {
          float w0 = wv[j * 16 + w], w1 = wv[(16 + j) * 16 + w];
          bs0 += vr[j * 3 + 0] * w0; bs1 += vr[j * 3 + 1] * w0; bs2 += vr[j * 3 + 2] * w0;
          bd0 += vr[j * 3 + 0] * w1; bd1 += vr[j * 3 + 1] * w1; bd2 += vr[j * 3 + 2] * w1;
        }
        union { short sh[4]; intx2 v2; } ub, ud2;
        ub.sh[0] = f2bf(bs0); ub.sh[1] = f2bf(bs1); ub.sh[2] = f2bf(bs2); ub.sh[3] = 0;
        ud2.sh[0] = f2bf(bd0); ud2.sh[1] = f2bf(bd1); ud2.sh[2] = f2bf(bd2); ud2.sh[3] = 0;
        *(intx2*)(Bsrc + (size_t)node * 64 + w * 4) = ub.v2;
        *(intx2*)(Bdst + (size_t)node * 64 + w * 4) = ud2.v2;
      }
    }
  }
}

// ------- edge message kernel (R3 structure + XCD-affine window swizzle) -------
// 64 sorted edges/block, 4 waves share the window; per-wave run-segmented
// packed-atomic flushes (proven R3 body). Window remap gives each XCD a
// CONTIGUOUS dst range so agg lines stay resident in one XCD's L2
// (no cross-XCD atomic line bouncing).
__global__ __launch_bounds__(256, 8) void gvp_edge(
    const int* __restrict__ perm, const int* __restrict__ sd,
    const float* __restrict__ lev, const float* __restrict__ es,
    const short* __restrict__ w1et, const float* __restrict__ wlen,
    const short* __restrict__ w2gt, const short* __restrict__ Asrc,
    const short* __restrict__ Adst, const short* __restrict__ Bsrc,
    const short* __restrict__ Bdst, const float* __restrict__ cg,
    const float* __restrict__ wv, short* __restrict__ agg_s,
    short* __restrict__ agg_v) {
  __shared__ __align__(16) short lh_all[4 * 16 * 136];  // per-wave silu tiles
  __shared__ int lpe[64];
  __shared__ int lsrc[64];
  __shared__ int ldst[64];
  __shared__ float lev4[64][4];  // x,y,z,len (pre-sorted table)

  const int tid = threadIdx.x;
  const int wid = tid >> 6;
  const int lane = tid & 63;
  const int quad = lane >> 4;
  const int l16 = lane & 15;
  // XCD-affine swizzle: bid%8 -> XCD (hw round-robin); give XCD k windows
  // [k*1250, (k+1)*1250) = contiguous dst range. Bijective (10000%8==0).
  const int bid = blockIdx.x;
  const int e0 = ((bid & 7) * XCD_CHUNK + (bid >> 3)) * 64;

  if (tid < 64) {
    intx2 p = *(const intx2*)(sd + (size_t)(e0 + tid) * 2);
    lsrc[tid] = p[0];
    ldst[tid] = p[1];
  } else if (tid < 128) {
    int er = tid - 64;
    floatx4 q = *(const floatx4*)(lev + (size_t)(e0 + er) * 4);
    lev4[er][0] = q[0]; lev4[er][1] = q[1]; lev4[er][2] = q[2]; lev4[er][3] = q[3];
  } else if (tid < 192) {
    int er = tid - 128;
    lpe[er] = perm[e0 + er];
  }
  __syncthreads();  // the only block barrier

  short* lh = lh_all + wid * 2176;

  // ---- GEMM1e: edge_s @ W1e (K=32), rows via perm (128B rows = full lines) ----
  const int erow = wid * 16 + l16;
  const int pe = lpe[erow];
  const float* ep = es + (size_t)pe * 32 + quad * 8;
  floatx4 ea = *(const floatx4*)ep;
  floatx4 eb = *(const floatx4*)(ep + 4);
  shortx8 afrag;
#pragma unroll
  for (int j = 0; j < 4; j++) { afrag[j] = f2bf(ea[j]); afrag[4 + j] = f2bf(eb[j]); }
  floatx4 acc[8];
#pragma unroll
  for (int nt = 0; nt < 8; nt++) {
    shortx8 b = *(const shortx8*)(w1et + (nt * 16 + l16) * 32 + quad * 8);
    floatx4 z = {0.f, 0.f, 0.f, 0.f};
    acc[nt] = mfma16(afrag, b, z);
  }

  // ---- this lane's 4 edge rows ----
  int srcn[4], dstn[4];
  float lenr[4];
#pragma unroll
  for (int i = 0; i < 4; i++) {
    int r = wid * 16 + quad * 4 + i;
    srcn[i] = lsrc[r]; dstn[i] = ldst[r]; lenr[i] = lev4[r][3];
  }

  // ---- h += A_src[src] + A_dst[dst] (bf16 gathers, f32 add; dst runs L1-hot) ----
#pragma unroll
  for (int i = 0; i < 4; i++) {
    shortx8 s8 = *(const shortx8*)(Asrc + (size_t)srcn[i] * 128 + l16 * 8);
    shortx8 d8 = *(const shortx8*)(Adst + (size_t)dstn[i] * 128 + l16 * 8);
#pragma unroll
    for (int nt = 0; nt < 8; nt++) acc[nt][i] += bf2f(s8[nt]) + bf2f(d8[nt]);
  }
  // ---- h += len * wlen[col] ----
#pragma unroll
  for (int nt = 0; nt < 8; nt++) {
    float wl = wlen[nt * 16 + l16];
#pragma unroll
    for (int i = 0; i < 4; i++) acc[nt][i] += lenr[i] * wl;
  }

  // ---- silu -> per-wave lh (bf16); lh is both gate-GEMM input and agg source ----
#pragma unroll
  for (int nt = 0; nt < 8; nt++)
#pragma unroll
    for (int i = 0; i < 4; i++) {
      float h = acc[nt][i];
      lh[(quad * 4 + i) * 136 + nt * 16 + l16] = f2bf(h * sigm(h));
    }

  // ---- gate logits = silu(h) @ W2g (K=128) ----
  floatx4 acc3 = {0.f, 0.f, 0.f, 0.f};
#pragma unroll
  for (int kc = 0; kc < 4; kc++) {
    shortx8 a = *(const shortx8*)(lh + l16 * 136 + kc * 32 + quad * 8);
    shortx8 b = *(const shortx8*)(w2gt + l16 * 128 + kc * 32 + quad * 8);
    acc3 = mfma16(a, b, acc3);
  }

  // ---- gated vproj into registers ----
  float wv32v = wv[32 * 16 + l16];
  float cgv = cg[l16];
  float gv[4][3];
#pragma unroll
  for (int i = 0; i < 4; i++) {
    int r = wid * 16 + quad * 4 + i;
    shortx4 bs = *(const shortx4*)(Bsrc + (size_t)srcn[i] * 64 + l16 * 4);
    shortx4 bd = *(const shortx4*)(Bdst + (size_t)dstn[i] * 64 + l16 * 4);
    float vx = bf2f(bs[0]) + bf2f(bd[0]) + lev4[r][0] * wv32v;
    float vy = bf2f(bs[1]) + bf2f(bd[1]) + lev4[r][1] * wv32v;
    float vz = bf2f(bs[2]) + bf2f(bd[2]) + lev4[r][2] * wv32v;
    float g = sigm(acc3[i] + cgv);
    gv[i][0] = g * vx; gv[i][1] = g * vy; gv[i][2] = g * vz;
  }

  // ---- run-segmented reduction: one atomic set per equal-dst run (per wave) ----
  const int rbase = wid * 16;
  int r = 0;
  while (r < 16) {
    int d = ldst[rbase + r];
    int r2 = r + 1;
    while (r2 < 16 && ldst[rbase + r2] == d) ++r2;
    // agg_s (silu sums): lane owns cols {2*lane, 2*lane+1}; f32 pre-sum over run
    float s0 = 0.f, s1 = 0.f;
    for (int row = r; row < r2; ++row) {
      int pv = *(const int*)(lh + row * 136 + 2 * lane);
      s0 += bf2f((short)(pv & 0xffff));
      s1 += bf2f((short)((unsigned)pv >> 16));
    }
    atom_pk(agg_s + (size_t)d * 128 + 2 * lane, pack2bf(s0, s1));
    // agg_v: per-lane masked partials, quad-sum via shuffles, quad0 atomics
    float vx = 0.f, vy = 0.f, vz = 0.f;
#pragma unroll
    for (int i = 0; i < 4; ++i) {
      int row = quad * 4 + i;
      if (row >= r && row < r2) { vx += gv[i][0]; vy += gv[i][1]; vz += gv[i][2]; }
    }
    vx += __shfl_xor(vx, 16); vy += __shfl_xor(vy, 16); vz += __shfl_xor(vz, 16);
    vx += __shfl_xor(vx, 32); vy += __shfl_xor(vy, 32); vz += __shfl_xor(vz, 32);
    if (quad == 0) {
      short* ap = agg_v + (size_t)d * 64 + l16 * 4;
      atom_pk(ap, pack2bf(vx, vy));
      atom_pk(ap + 2, pack2bf(vz, 0.f));
    }
    r = r2;
  }
}

// ---------------- node update kernel (2 barriers) ----------------
__global__ __launch_bounds__(256) void gvp_node(
    const float* __restrict__ s, const float* __restrict__ v,
    const short* __restrict__ agg_s, const short* __restrict__ agg_v,
    const int* __restrict__ cnt, const float* __restrict__ b2u,
    const short* __restrict__ u1t, const short* __restrict__ u2t,
    const short* __restrict__ ugt, const short* __restrict__ uwvt,
    const float* __restrict__ b1, const float* __restrict__ b2,
    const float* __restrict__ bg, const float* __restrict__ lng,
    const float* __restrict__ lnb, float* __restrict__ out_s,
    float* __restrict__ out_v) {
  __shared__ __align__(16) short lx[64 * 288];  // X2 [64][288]; overlays: lh + lb
  const int tid = threadIdx.x;
  const int wid = tid >> 6;
  const int lane = tid & 63;
  const int quad = lane >> 4;
  const int l16 = lane & 15;
  const int nb0 = blockIdx.x * 64;

  float cntf[4];
#pragma unroll
  for (int i = 0; i < 4; i++) {
    int node = nb0 + wid * 16 + quad * 4 + i;
    cntf[i] = (node < NN) ? (float)cnt[node] : 0.f;
  }

  intx4 z4 = {0, 0, 0, 0};
#pragma unroll
  for (int i = 0; i < 4; i++) {
    int idx = tid + i * 256;
    int r = idx >> 4, cc = (idx & 15) * 8;
    int node = nb0 + r;
    union { short sh[8]; intx4 v4; } u;
    u.v4 = z4;
    if (node < NN) {
      const float* sp = s + (size_t)node * 128 + cc;
      floatx4 f0 = *(const floatx4*)sp, f1 = *(const floatx4*)(sp + 4);
#pragma unroll
      for (int j = 0; j < 4; j++) { u.sh[j] = f2bf(f0[j]); u.sh[4 + j] = f2bf(f1[j]); }
    }
    *(intx4*)(lx + r * 288 + cc) = u.v4;
  }
#pragma unroll
  for (int i = 0; i < 4; i++) {  // agg_silu: already bf16, straight copy
    int idx = tid + i * 256;
    int r = idx >> 4, cc = (idx & 15) * 8;
    int node = nb0 + r;
    intx4 val = z4;
    if (node < NN) val = *(const intx4*)(agg_s + (size_t)node * 128 + cc);
    *(intx4*)(lx + r * 288 + 128 + cc) = val;
  }
  {
    int r = tid >> 2, p = tid & 3;
    int node = nb0 + r;
    int w0 = (p & 1) * 8;
    if (p < 2) {
#pragma unroll
      for (int w = 0; w < 8; w++) {
        float nv = 0.f;
        if (node < NN) {
          const float* vp = v + (size_t)node * 48 + (w0 + w) * 3;
          nv = sqrtf(fmaxf(vp[0] * vp[0] + vp[1] * vp[1] + vp[2] * vp[2], 1e-8f));
        }
        lx[r * 288 + 256 + w0 + w] = f2bf(nv);
      }
    } else {
#pragma unroll
      for (int w = 0; w < 8; w++) {
        float nv = 0.f;
        if (node < NN) {
          const short* ap = agg_v + (size_t)node * 64 + (w0 + w) * 4;
          float x = bf2f(ap[0]), y = bf2f(ap[1]), zz = bf2f(ap[2]);
          nv = sqrtf(fmaxf(x * x + y * y + zz * zz, 1e-8f));
        }
        lx[r * 288 + 272 + w0 + w] = f2bf(nv);
      }
    }
  }
  __syncthreads();  // X2 ready

  // ---- GEMM1 (K=288), B-frags from global u1t ----
  floatx4 acc[8] = {};
#pragma unroll
  for (int kc = 0; kc < 9; kc++) {
    shortx8 a = *(const shortx8*)(lx + (wid * 16 + l16) * 288 + kc * 32 + quad * 8);
#pragma unroll
    for (int nt = 0; nt < 8; nt++) {
      shortx8 b = *(const shortx8*)(u1t + (size_t)(nt * 16 + l16) * 288 + kc * 32 + quad * 8);
      acc[nt] = mfma16(a, b, acc[nt]);
    }
  }
  __syncthreads();  // X2 dead; safe to overlay lh/lb

  short* lh = lx;  // [64][136] bf16
  short* lb = lx + 8704 + wid * 1536;  // per-wave [3 comp][16 node][32 k] bf16
#pragma unroll
  for (int nt = 0; nt < 8; nt++)
#pragma unroll
    for (int i = 0; i < 4; i++) {
      int row = wid * 16 + quad * 4 + i;
      int col = nt * 16 + l16;
      float h = acc[nt][i] + b1[col] + cntf[i] * b2u[col];
      lh[row * 136 + col] = f2bf(h * sigm(h));
    }

  // ---- GEMM2 (K=128), B from global u2t ----
  floatx4 acc2[8] = {};
#pragma unroll
  for (int kc = 0; kc < 4; kc++) {
    shortx8 a = *(const shortx8*)(lh + (wid * 16 + l16) * 136 + kc * 32 + quad * 8);
#pragma unroll
    for (int nt = 0; nt < 8; nt++) {
      shortx8 b = *(const shortx8*)(u2t + (size_t)(nt * 16 + l16) * 128 + kc * 32 + quad * 8);
      acc2[nt] = mfma16(a, b, acc2[nt]);
    }
  }

  // ---- epilogue: ds -> lh (gate input); t = s + ds in acc2 ----
#pragma unroll
  for (int nt = 0; nt < 8; nt++)
#pragma unroll
    for (int i = 0; i < 4; i++) {
      int row = wid * 16 + quad * 4 + i;
      int col = nt * 16 + l16;
      int node = nb0 + row;
      float ds = acc2[nt][i] + b2[col];
      lh[row * 136 + col] = f2bf(ds);
      float sv = (node < NN) ? s[(size_t)node * 128 + col] : 0.f;
      acc2[nt][i] = sv + ds;
    }

  // ---- LayerNorm + out_s store ----
#pragma unroll
  for (int i = 0; i < 4; i++) {
    float sum = 0.f, sq = 0.f;
#pragma unroll
    for (int nt = 0; nt < 8; nt++) { float t = acc2[nt][i]; sum += t; sq += t * t; }
    for (int off2 = 1; off2 < 16; off2 <<= 1) {
      sum += __shfl_xor(sum, off2);
      sq += __shfl_xor(sq, off2);
    }
    float mean = sum * (1.f / 128.f);
    float var = sq * (1.f / 128.f) - mean * mean;
    float inv = rsqrtf(fmaxf(var, 0.f) + 1e-5f);
    int node = nb0 + wid * 16 + quad * 4 + i;
    if (node < NN) {
#pragma unroll
      for (int nt = 0; nt < 8; nt++) {
        int col = nt * 16 + l16;
        float o = (acc2[nt][i] - mean) * inv * lng[col] + lnb[col];
        out_s[(size_t)node * 128 + col] = o;
      }
    }
  }

  // ---- per-wave u_v_in tile lb [3][16 node][32 ch] bf16 (wave-local) ----
  {
    int e = lane >> 2, p = lane & 3;
    int node = nb0 + wid * 16 + e;
    short* lbe = lb + e * 32;
    if (p < 2) {  // v channels k = p*8 .. p*8+7
      float vr[24];
      if (node < NN) {
        const floatx4* sp = (const floatx4*)(v + (size_t)node * 48 + p * 24);
#pragma unroll
        for (int j = 0; j < 6; j++) {
          floatx4 f = sp[j];
          vr[j * 4 + 0] = f[0]; vr[j * 4 + 1] = f[1];
          vr[j * 4 + 2] = f[2]; vr[j * 4 + 3] = f[3];
        }
      } else {
#pragma unroll
        for (int j = 0; j < 24; j++) vr[j] = 0.f;
      }
#pragma unroll
      for (int k = 0; k < 8; k++)
#pragma unroll
        for (int c = 0; c < 3; c++)
          lbe[c * 512 + p * 8 + k] = f2bf(vr[k * 3 + c]);
    } else {  // agg_v channels k = 16 + (p-2)*8 ..
      int wbase = (p - 2) * 8;
#pragma unroll
      for (int w = 0; w < 8; w++) {
        shortx4 av = {0, 0, 0, 0};
        if (node < NN) av = *(const shortx4*)(agg_v + (size_t)node * 64 + (wbase + w) * 4);
#pragma unroll
        for (int c = 0; c < 3; c++)
          lbe[c * 512 + 16 + wbase + w] = av[c];
      }
    }
  }

  // ---- GEMM3: gate logits = ds @ Ug (B from global) ----
  floatx4 acc3 = {0.f, 0.f, 0.f, 0.f};
#pragma unroll
  for (int kc = 0; kc < 4; kc++) {
    shortx8 a = *(const shortx8*)(lh + (wid * 16 + l16) * 136 + kc * 32 + quad * 8);
    shortx8 b = *(const shortx8*)(ugt + l16 * 128 + kc * 32 + quad * 8);
    acc3 = mfma16(a, b, acc3);
  }

  // ---- dv via 3 MFMAs ----
  float vm[4][3];
#pragma unroll
  for (int c = 0; c < 3; c++) {
    shortx8 a = *(const shortx8*)(lb + c * 512 + l16 * 32 + quad * 8);
    shortx8 b = *(const shortx8*)(uwvt + l16 * 32 + quad * 8);
    floatx4 z = {0.f, 0.f, 0.f, 0.f};
    floatx4 rr = mfma16(a, b, z);
#pragma unroll
    for (int i = 0; i < 4; i++) vm[i][c] = rr[i];
  }

  // ---- residual store ----
#pragma unroll
  for (int i = 0; i < 4; i++) {
    int node = nb0 + wid * 16 + quad * 4 + i;
    if (node < NN) {
      float g = sigm(acc3[i] + bg[l16]);
      size_t base = (size_t)node * 48 + l16 * 3;
      out_v[base + 0] = v[base + 0] + g * vm[i][0];
      out_v[base + 1] = v[base + 1] + g * vm[i][1];
      out_v[base + 2] = v[base + 2] + g * vm[i][2];
    }
  }
}

extern "C" void kernel_launch(void* const* d_in, const int* in_sizes, int n_in,
                              void* d_out, int out_size, void* d_ws, size_t ws_size,
                              hipStream_t stream) {
  const float* s = (const float*)d_in[0];
  const float* v = (const float*)d_in[1];
  const int* eidx = (const int*)d_in[2];
  const float* es = (const float*)d_in[3];
  const float* ev = (const float*)d_in[4];
  const float* mW1 = (const float*)d_in[5];
  const float* mb1 = (const float*)d_in[6];
  const float* mW2 = (const float*)d_in[7];
  const float* mb2 = (const float*)d_in[8];
  const float* mWv = (const float*)d_in[9];
  const float* mWg = (const float*)d_in[10];
  const float* mbg = (const float*)d_in[11];
  const float* uW1 = (const float*)d_in[12];
  const float* ub1 = (const float*)d_in[13];
  const float* uW2 = (const float*)d_in[14];
  const float* ub2 = (const float*)d_in[15];
  const float* uWv = (const float*)d_in[16];
  const float* uWg = (const float*)d_in[17];
  const float* ubg = (const float*)d_in[18];
  const float* lng = (const float*)d_in[19];
  const float* lnb = (const float*)d_in[20];

  char* ws = (char*)d_ws;
  short* w1et = (short*)(ws + W1ET_OFF);
  float* wlen = (float*)(ws + WLEN_OFF);
  short* wcat = (short*)(ws + WCAT_OFF);
  short* w2gt = (short*)(ws + W2GT_OFF);
  float* cg = (float*)(ws + CG_OFF);
  short* u1t = (short*)(ws + U1T_OFF);
  float* b2u = (float*)(ws + B2U_OFF);
  short* u2t = (short*)(ws + U2T_OFF);
  short* ugt = (short*)(ws + UGT_OFF);
  short* uwvt = (short*)(ws + UWVT_OFF);
  short* Asrc = (short*)(ws + ASRC_OFF);
  short* Adst = (short*)(ws + ADST_OFF);
  short* Bsrc = (short*)(ws + BSRC_OFF);
  short* Bdst = (short*)(ws + BDST_OFF);
  short* agg_s = (short*)(ws + AGG_S_OFF);
  short* agg_v = (short*)(ws + AGG_V_OFF);
  int* cnt = (int*)(ws + CNT_OFF);
  int* off = (int*)(ws + OFF_OFF);
  int* perm = (int*)(ws + PERM_OFF);
  int* sd = (int*)(ws + SD_OFF);
  float* lev = (float*)(ws + LEV_OFF);

  hipMemsetAsync(ws + CNT_OFF, 0, (size_t)NN * 4, stream);  // cnt only (80KB)
  gvp_prep<<<PREP_BLOCKS + HIST_BLOCKS + AGGZ_BLOCKS, 256, 0, stream>>>(
      mW1, mW2, mWg, mb2, mbg, uW1, uW2, uWg, uWv, eidx,
      w1et, wlen, wcat, w2gt, cg, u1t, b2u, u2t, ugt, uwvt, cnt, agg_s);
  gvp_scan<<<1, 256, 0, stream>>>(cnt, off);
  gvp_nodepre<<<SCAT_BLOCKS + NODE_BLOCKS, 256, 0, stream>>>(
      eidx, ev, off, perm, sd, lev, s, v, wcat, mb1, mWv, Asrc, Adst, Bsrc, Bdst);
  gvp_edge<<<EDGE_BLOCKS, 256, 0, stream>>>(perm, sd, lev, es, w1et, wlen, w2gt,
                                            Asrc, Adst, Bsrc, Bdst, cg, mWv,
                                            agg_s, agg_v);
  gvp_node<<<NODE_BLOCKS, 256, 0, stream>>>(s, v, agg_s, agg_v, cnt, b2u,
                                            u1t, u2t, ugt, uwvt, ub1, ub2, ubg,
                                            lng, lnb, (float*)d_out,
                                            (float*)d_out + (size_t)NN * 128);
}